// Round 1
// baseline (23628.108 us; speedup 1.0000x reference)
//
#include <hip/hip_runtime.h>
#include <hip/hip_bf16.h>

typedef __bf16 bf16;
typedef __attribute__((ext_vector_type(8))) __bf16 bf16x8;
typedef __attribute__((ext_vector_type(4))) __bf16 bf16x4;
typedef __attribute__((ext_vector_type(4))) float f32x4;

#define T_STEPS 512
#define NWG 256

// workspace byte offsets
#define WS_CNT   0         //  4096 B  (uint cnt[1024]): root at [0], leaves at [32+16*l... spaced 128B]
#define WS_H     4096      // 65536 B  h_glob [32][1024] bf16
#define WS_BTOT  69632     // 16384 B  btot [4][1024] f32
#define WS_XBF   86016     // 16777216 B  Xbf [512][32][512] bf16
#define WS_BPACK 16863232  // 12582912 B  Bpack fragments
// total 29446144 B (~28.1 MB)

// ---------- pack X: Xbf[t][b][d] = bf16(X[b][t][d]) ----------
__global__ void k_xpack(const float* __restrict__ X, bf16* __restrict__ Xbf) {
    int gid = blockIdx.x * 256 + threadIdx.x;   // 2,097,152 threads, 4 elems each
    int o = gid << 2;
    int d = o & 511, b = (o >> 9) & 31, t = o >> 14;
    const float4 v = *(const float4*)(X + (size_t)(b * 512 + t) * 512 + d);
    bf16x4 r;
    r.x = (bf16)v.x; r.y = (bf16)v.y; r.z = (bf16)v.z; r.w = (bf16)v.w;
    *(bf16x4*)(Xbf + (size_t)(t * 32 + b) * 512 + d) = r;
}

// ---------- pack weights into MFMA fragment order ----------
// layout: [cg 128][wid 4][m 12][nt 2][lane 64][j 8]
// value  = B[k][col],  k = (wid*12+m)*32 + (lane>>4)*8 + j,  col = nt*16 + (lane&15)
// B[k][col]: col -> (g = col>>3, hl = col&7, h = cg*8+hl); k<1024 -> W_g[h][k], else U_g[h][k-1024]
__global__ void k_bpack(const float* __restrict__ W0, const float* __restrict__ W1,
                        const float* __restrict__ W2, const float* __restrict__ W3,
                        const float* __restrict__ U0, const float* __restrict__ U1,
                        const float* __restrict__ U2, const float* __restrict__ U3,
                        bf16* __restrict__ Bp) {
    int gid = blockIdx.x * 256 + threadIdx.x;   // 786,432 threads, one fragment (8 elems) each
    int lane = gid & 63; int idx = gid >> 6;
    int nt = idx & 1;  idx >>= 1;
    int m  = idx % 12; idx /= 12;
    int wid = idx & 3; idx >>= 2;
    int cg = idx;                                 // 0..127
    int mk = wid * 12 + m;
    int kbase = mk * 32 + ((lane >> 4) << 3);
    int col = nt * 16 + (lane & 15);
    int g = col >> 3, hl = col & 7;
    int h = cg * 8 + hl;
    const float* Wg = (g == 0) ? W0 : (g == 1) ? W1 : (g == 2) ? W2 : W3;
    const float* Ug = (g == 0) ? U0 : (g == 1) ? U1 : (g == 2) ? U2 : U3;
    const float* src = (kbase < 1024) ? (Wg + (size_t)h * 1024 + kbase)
                                      : (Ug + (size_t)h * 512 + (kbase - 1024));
    float4 v0 = *(const float4*)(src);
    float4 v1 = *(const float4*)(src + 4);
    bf16x8 r;
    r[0] = (bf16)v0.x; r[1] = (bf16)v0.y; r[2] = (bf16)v0.z; r[3] = (bf16)v0.w;
    r[4] = (bf16)v1.x; r[5] = (bf16)v1.y; r[6] = (bf16)v1.z; r[7] = (bf16)v1.w;
    *(bf16x8*)(Bp + (size_t)gid * 8) = r;
}

// ---------- init: combined biases, zero h_glob, zero barrier counters ----------
__global__ void k_init(const float* bWf, const float* bUf, const float* bWi, const float* bUi,
                       const float* bWo, const float* bUo, const float* bWc, const float* bUc,
                       float* btot, bf16* hglob, unsigned* cnt) {
    int gid = blockIdx.x * 256 + threadIdx.x;   // 4096 threads
    int g = gid >> 10, h = gid & 1023;
    const float* bW = (g == 0) ? bWf : (g == 1) ? bWi : (g == 2) ? bWo : bWc;
    const float* bU = (g == 0) ? bUf : (g == 1) ? bUi : (g == 2) ? bUo : bUc;
    btot[gid] = bW[h] + bU[h];
    uint4 z; z.x = 0u; z.y = 0u; z.z = 0u; z.w = 0u;
    ((uint4*)hglob)[gid] = z;                   // 4096 * 16B = 65536 B
    if (gid < 1024) cnt[gid] = 0u;
}

// ---------- persistent scan kernel ----------
// 256 WGs x 256 threads. WG = (p = batch-half, cg = 8 h-indices).
// 4 waves split K=1536 (k<1024: h-part, k>=1024: fused x-projection), 2 N-tiles of 16 cols.
__global__ __launch_bounds__(256, 1) void k_scan(
        const bf16* __restrict__ Bp, const bf16* __restrict__ Xbf,
        const float* __restrict__ btot, bf16* hglob, unsigned* cnt,
        float* __restrict__ out) {
    const int tid = threadIdx.x;
    const int lane = tid & 63, wid = tid >> 6;
    const int wg = blockIdx.x;
    const int p = wg & 1, cg = wg >> 1;

    // preload this wave's 24 B-fragments into registers (resident for whole scan)
    bf16x8 bq[24];
    {
        const bf16x8* fragp = (const bf16x8*)Bp;
        size_t base = ((size_t)(cg * 4 + wid) * 24) * 64 + lane;
#pragma unroll
        for (int i = 0; i < 24; ++i) bq[i] = fragp[base + (size_t)i * 64];
    }

    const int arow = (lane & 15) + p * 16;        // batch row for A fragments
    const int koff = (lane >> 4) << 3;
    const bf16* hb = hglob + arow * 1024 + koff;

    // elementwise thread mapping (threads 0..127: one (batch row, h-index) each)
    const bool ew = tid < 128;
    const int erow = tid & 15;
    const int ehl = (tid >> 4) & 7;
    const int hgl = cg * 8 + ehl;
    float bias0 = 0.f, bias1 = 0.f, bias2 = 0.f, bias3 = 0.f;
    if (ew) {
        bias0 = btot[hgl];
        bias1 = btot[1024 + hgl];
        bias2 = btot[2048 + hgl];
        bias3 = btot[3072 + hgl];
    }
    const int b_glob = p * 16 + erow;
    float* outp = out + (size_t)b_glob * 512 * 1024 + hgl;
    bf16* hstp = hglob + b_glob * 1024 + hgl;
    float cst = 0.f;

    __shared__ float part[4][2][64][4];

    unsigned* root = cnt;
    unsigned* leaf = cnt + 32 + (wg >> 4) * 32;   // 16 leaves, 128B apart

    for (int t = 0; t < T_STEPS; ++t) {
        asm volatile("" ::: "memory");
        const bf16* xb = Xbf + (size_t)(t * 32 + arow) * 512 + koff;
        f32x4 acc0 = {0.f, 0.f, 0.f, 0.f};
        f32x4 acc1 = {0.f, 0.f, 0.f, 0.f};
#pragma unroll
        for (int m = 0; m < 12; ++m) {
            const int mk = wid * 12 + m;          // wave-uniform
            const bf16* ap = (mk < 32) ? (hb + mk * 32) : (xb + (mk * 32 - 1024));
            bf16x8 a = *(const bf16x8*)ap;
            acc0 = __builtin_amdgcn_mfma_f32_16x16x32_bf16(a, bq[2 * m],     acc0, 0, 0, 0);
            acc1 = __builtin_amdgcn_mfma_f32_16x16x32_bf16(a, bq[2 * m + 1], acc1, 0, 0, 0);
        }
        *(f32x4*)(&part[wid][0][lane][0]) = acc0;
        *(f32x4*)(&part[wid][1][lane][0]) = acc1;
        __syncthreads();

        if (ew) {
            const int li0 = ((erow >> 2) << 4) | ehl;   // C/D: col=lane&15, row=(lane>>4)*4+reg
            const int li1 = li0 | 8;
            const int reg = erow & 3;
            float a0 = bias0, a1 = bias1, a2 = bias2, a3 = bias3;
#pragma unroll
            for (int w = 0; w < 4; ++w) {
                a0 += part[w][0][li0][reg];
                a1 += part[w][0][li1][reg];
                a2 += part[w][1][li0][reg];
                a3 += part[w][1][li1][reg];
            }
            float f  = 1.f / (1.f + __expf(-a0));
            float i  = 1.f / (1.f + __expf(-a1));
            float o  = 1.f / (1.f + __expf(-a2));
            float cb = 2.f / (1.f + __expf(-2.f * a3)) - 1.f;
            cst = f * cst + i * cb;
            float th = 2.f / (1.f + __expf(-2.f * cst)) - 1.f;
            float hv = o * th;
            *hstp = (bf16)hv;                     // recurrent state (bf16)
            outp[(size_t)t * 1024] = hv;          // output (fp32)
        }

        if (t + 1 < T_STEPS) {
            __threadfence();                      // release h stores (agent scope)
            __syncthreads();
            if (tid == 0) {
                unsigned old = __hip_atomic_fetch_add(leaf, 1u, __ATOMIC_ACQ_REL,
                                                      __HIP_MEMORY_SCOPE_AGENT);
                if ((old & 15u) == 15u)
                    __hip_atomic_fetch_add(root, 1u, __ATOMIC_ACQ_REL,
                                           __HIP_MEMORY_SCOPE_AGENT);
                const unsigned target = 16u * (unsigned)(t + 1);
                while (__hip_atomic_load(root, __ATOMIC_RELAXED,
                                         __HIP_MEMORY_SCOPE_AGENT) < target)
                    __builtin_amdgcn_s_sleep(2);
            }
            __syncthreads();
            __threadfence();                      // acquire before next step's h reads
        }
    }
}

extern "C" void kernel_launch(void* const* d_in, const int* in_sizes, int n_in,
                              void* d_out, int out_size, void* d_ws, size_t ws_size,
                              hipStream_t stream) {
    const float* X   = (const float*)d_in[0];
    const float* Wf  = (const float*)d_in[1];
    const float* bWf = (const float*)d_in[2];
    const float* Uf  = (const float*)d_in[3];
    const float* bUf = (const float*)d_in[4];
    const float* Wi  = (const float*)d_in[5];
    const float* bWi = (const float*)d_in[6];
    const float* Ui  = (const float*)d_in[7];
    const float* bUi = (const float*)d_in[8];
    const float* Wo  = (const float*)d_in[9];
    const float* bWo = (const float*)d_in[10];
    const float* Uo  = (const float*)d_in[11];
    const float* bUo = (const float*)d_in[12];
    const float* Wc  = (const float*)d_in[13];
    const float* bWc = (const float*)d_in[14];
    const float* Uc  = (const float*)d_in[15];
    const float* bUc = (const float*)d_in[16];

    char* ws = (char*)d_ws;
    unsigned* cnt = (unsigned*)(ws + WS_CNT);
    bf16* hglob   = (bf16*)(ws + WS_H);
    float* btot   = (float*)(ws + WS_BTOT);
    bf16* Xbf     = (bf16*)(ws + WS_XBF);
    bf16* Bp      = (bf16*)(ws + WS_BPACK);
    float* out    = (float*)d_out;

    hipLaunchKernelGGL(k_init, dim3(16), dim3(256), 0, stream,
                       bWf, bUf, bWi, bUi, bWo, bUo, bWc, bUc, btot, hglob, cnt);
    hipLaunchKernelGGL(k_xpack, dim3(8192), dim3(256), 0, stream, X, Xbf);
    hipLaunchKernelGGL(k_bpack, dim3(3072), dim3(256), 0, stream,
                       Wf, Wi, Wo, Wc, Uf, Ui, Uo, Uc, Bp);
    hipLaunchKernelGGL(k_scan, dim3(NWG), dim3(256), 0, stream,
                       Bp, Xbf, btot, hglob, cnt, out);
}

// Round 2
// 1840.943 us; speedup vs baseline: 12.8348x; 12.8348x over previous
//
#include <hip/hip_runtime.h>
#include <hip/hip_bf16.h>

typedef __bf16 bf16;
typedef __attribute__((ext_vector_type(8))) __bf16 bf16x8;
typedef __attribute__((ext_vector_type(4))) __bf16 bf16x4;
typedef __attribute__((ext_vector_type(4))) float f32x4;
typedef __attribute__((ext_vector_type(4))) unsigned int u32x4;

#define T_STEPS 512
#define NWG 256

// workspace byte offsets
#define WS_CNT   0          //   4096 B  uint cnt[1024]: root at [0], leaves at [32 + g*32]
#define WS_H     4096       // 131072 B  h_glob: two buffers [2][32][1024] bf16
#define WS_BTOT  135168     //  16384 B  btot [4][1024] f32
#define WS_XBF   151552     // 16777216 B  Xbf [512][32][512] bf16
#define WS_BPACK 16928768   // 12582912 B  Bpack fragments
// total 29511680 B (~28.1 MB)

// ---------- pack X: Xbf[t][b][d] = bf16(X[b][t][d]) ----------
__global__ void k_xpack(const float* __restrict__ X, bf16* __restrict__ Xbf) {
    int gid = blockIdx.x * 256 + threadIdx.x;   // 2,097,152 threads, 4 elems each
    int o = gid << 2;
    int d = o & 511, b = (o >> 9) & 31, t = o >> 14;
    const float4 v = *(const float4*)(X + (size_t)(b * 512 + t) * 512 + d);
    bf16x4 r;
    r.x = (bf16)v.x; r.y = (bf16)v.y; r.z = (bf16)v.z; r.w = (bf16)v.w;
    *(bf16x4*)(Xbf + (size_t)(t * 32 + b) * 512 + d) = r;
}

// ---------- pack weights into MFMA fragment order ----------
// layout: [cg 128][mk 48][nt 2][lane 64][j 8]
// value  = B[k][col],  k = mk*32 + (lane>>4)*8 + j,  col = nt*16 + (lane&15)
// col -> (g = col>>3, hl = col&7, h = cg*8+hl); k<1024 -> W_g[h][k], else U_g[h][k-1024]
__global__ void k_bpack(const float* __restrict__ W0, const float* __restrict__ W1,
                        const float* __restrict__ W2, const float* __restrict__ W3,
                        const float* __restrict__ U0, const float* __restrict__ U1,
                        const float* __restrict__ U2, const float* __restrict__ U3,
                        bf16* __restrict__ Bp) {
    int gid = blockIdx.x * 256 + threadIdx.x;   // 786,432 threads, one fragment (8 elems) each
    int lane = gid & 63; int idx = gid >> 6;
    int nt = idx & 1;  idx >>= 1;
    int mk = idx % 48; int cg = idx / 48;       // cg 0..127
    int kbase = mk * 32 + ((lane >> 4) << 3);
    int col = nt * 16 + (lane & 15);
    int g = col >> 3, hl = col & 7;
    int h = cg * 8 + hl;
    const float* Wg = (g == 0) ? W0 : (g == 1) ? W1 : (g == 2) ? W2 : W3;
    const float* Ug = (g == 0) ? U0 : (g == 1) ? U1 : (g == 2) ? U2 : U3;
    const float* src = (kbase < 1024) ? (Wg + (size_t)h * 1024 + kbase)
                                      : (Ug + (size_t)h * 512 + (kbase - 1024));
    float4 v0 = *(const float4*)(src);
    float4 v1 = *(const float4*)(src + 4);
    bf16x8 r;
    r[0] = (bf16)v0.x; r[1] = (bf16)v0.y; r[2] = (bf16)v0.z; r[3] = (bf16)v0.w;
    r[4] = (bf16)v1.x; r[5] = (bf16)v1.y; r[6] = (bf16)v1.z; r[7] = (bf16)v1.w;
    *(bf16x8*)(Bp + (size_t)gid * 8) = r;
}

// ---------- init: combined biases, zero both h buffers, zero barrier counters ----------
__global__ void k_init(const float* bWf, const float* bUf, const float* bWi, const float* bUi,
                       const float* bWo, const float* bUo, const float* bWc, const float* bUc,
                       float* btot, bf16* hglob, unsigned* cnt) {
    int gid = blockIdx.x * 256 + threadIdx.x;   // 4096 threads
    int g = gid >> 10, h = gid & 1023;
    const float* bW = (g == 0) ? bWf : (g == 1) ? bWi : (g == 2) ? bWo : bWc;
    const float* bU = (g == 0) ? bUf : (g == 1) ? bUi : (g == 2) ? bUo : bUc;
    btot[gid] = bW[h] + bU[h];
    uint4 z; z.x = 0u; z.y = 0u; z.z = 0u; z.w = 0u;
    ((uint4*)hglob)[gid] = z;                   // 2 x 65536 B
    ((uint4*)hglob)[gid + 4096] = z;
    if (gid < 1024) cnt[gid] = 0u;
}

#define MFMA(a, b, c) __builtin_amdgcn_mfma_f32_16x16x32_bf16((a), (b), (c), 0, 0, 0)
#define BQ(i) __builtin_bit_cast(bf16x8, bqr[i])

// ---------- persistent scan kernel ----------
// 256 WGs x 256 threads. WG = (p = batch-half, cg = 8 h-indices x 4 gates = 32 cols).
// 4 waves each handle 8 h k-slices + 4 x k-slices; 2 N-tiles of 16 cols.
// Cross-WG exchange of h via sc0 sc1 (coherent-point) stores/loads — no cache fences.
__global__ __launch_bounds__(256, 1) void k_scan(
        const bf16* __restrict__ Bp, const bf16* __restrict__ Xbf,
        const float* __restrict__ btot, bf16* hglob, unsigned* cnt,
        float* __restrict__ out) {
    const int tid = threadIdx.x;
    const int lane = tid & 63, wid = tid >> 6;
    const int wg = blockIdx.x;
    const int p = wg & 1, cg = wg >> 1;

    // preload this wave's 24 B-fragments into registers; asm volatile loads cannot be
    // rematerialized, so they stay VGPR-resident for the whole scan.
    u32x4 bqr[24];
    {
#pragma unroll
        for (int i = 0; i < 24; ++i) {
            int mk = (i < 16) ? (wid * 8 + (i >> 1)) : (32 + wid * 4 + ((i - 16) >> 1));
            int nt = i & 1;
            const bf16* pfrag = Bp + ((((size_t)(cg * 48 + mk) * 2 + nt) * 64 + lane) << 3);
            asm volatile("global_load_dwordx4 %0, %1, off" : "=v"(bqr[i]) : "v"(pfrag));
        }
        asm volatile("s_waitcnt vmcnt(0)" ::: "memory");
        __builtin_amdgcn_sched_barrier(0);
    }

    const int arow = (lane & 15) + p * 16;        // batch row for A fragments
    const int koff = (lane >> 4) << 3;

    // elementwise thread mapping (threads 0..127: one (batch row, h-index) each)
    const bool ew = tid < 128;
    const int erow = tid & 15;
    const int ehl = (tid >> 4) & 7;
    const int hgl = cg * 8 + ehl;
    float bias0 = 0.f, bias1 = 0.f, bias2 = 0.f, bias3 = 0.f;
    if (ew) {
        bias0 = btot[hgl];
        bias1 = btot[1024 + hgl];
        bias2 = btot[2048 + hgl];
        bias3 = btot[3072 + hgl];
    }
    const int b_glob = p * 16 + erow;
    float* outp = out + (size_t)b_glob * 512 * 1024 + hgl;
    bf16* hstp = hglob + b_glob * 1024 + hgl;
    float cst = 0.f;

    __shared__ float part[4][2][64][4];

    unsigned* root = cnt;
    unsigned* leaf = cnt + 32 + (wg >> 4) * 32;   // 16 leaves, 128B apart

    for (int t = 0; t < T_STEPS; ++t) {
        // ---- phase A: x-projection part for step t (independent of h) ----
        f32x4 acc0 = {0.f, 0.f, 0.f, 0.f};
        f32x4 acc1 = {0.f, 0.f, 0.f, 0.f};
        {
            const bf16* xb = Xbf + ((size_t)(t * 32 + arow) << 9) + koff;
#pragma unroll
            for (int m = 0; m < 4; ++m) {
                bf16x8 a = *(const bf16x8*)(xb + ((wid * 4 + m) << 5));
                acc0 = MFMA(a, BQ(16 + 2 * m), acc0);
                acc1 = MFMA(a, BQ(17 + 2 * m), acc1);
            }
        }

        // ---- wait for h(t) (produced at end of step t-1 by all WGs) ----
        if (t > 0) {
            if (tid == 0) {
                const unsigned target = 16u * (unsigned)t;
                while (__hip_atomic_load(root, __ATOMIC_RELAXED,
                                         __HIP_MEMORY_SCOPE_AGENT) < target)
                    __builtin_amdgcn_s_sleep(1);
            }
            __syncthreads();
        }

        // ---- phase B: recurrent part; h loads bypass L1/L2 (coherent point) ----
        {
            const bf16* hbuf = hglob + ((size_t)(t & 1) << 15) + arow * 1024 + koff;
            u32x4 av[8];
#pragma unroll
            for (int m = 0; m < 8; ++m) {
                const bf16* ph = hbuf + ((wid * 8 + m) << 5);
                asm volatile("global_load_dwordx4 %0, %1, off sc0 sc1"
                             : "=v"(av[m]) : "v"(ph) : "memory");
            }
            asm volatile("s_waitcnt vmcnt(0)" ::: "memory");
            __builtin_amdgcn_sched_barrier(0);
#pragma unroll
            for (int m = 0; m < 8; ++m) {
                bf16x8 a = __builtin_bit_cast(bf16x8, av[m]);
                acc0 = MFMA(a, BQ(2 * m), acc0);
                acc1 = MFMA(a, BQ(2 * m + 1), acc1);
            }
        }
        *(f32x4*)(&part[wid][0][lane][0]) = acc0;
        *(f32x4*)(&part[wid][1][lane][0]) = acc1;
        __syncthreads();

        if (ew) {
            const int li0 = ((erow >> 2) << 4) | ehl;   // C/D: col=lane&15, row=(lane>>4)*4+reg
            const int li1 = li0 | 8;
            const int reg = erow & 3;
            float a0 = bias0, a1 = bias1, a2 = bias2, a3 = bias3;
#pragma unroll
            for (int w = 0; w < 4; ++w) {
                a0 += part[w][0][li0][reg];
                a1 += part[w][0][li1][reg];
                a2 += part[w][1][li0][reg];
                a3 += part[w][1][li1][reg];
            }
            float f  = 1.f / (1.f + __expf(-a0));
            float i  = 1.f / (1.f + __expf(-a1));
            float o  = 1.f / (1.f + __expf(-a2));
            float cb = 2.f / (1.f + __expf(-2.f * a3)) - 1.f;
            cst = f * cst + i * cb;
            float th = 2.f / (1.f + __expf(-2.f * cst)) - 1.f;
            float hv = o * th;
            // h(t+1) -> buffer (t+1)&1, written through to the device coherent point
            bf16 hb16 = (bf16)hv;
            unsigned hv32 = (unsigned)__builtin_bit_cast(unsigned short, hb16);
            bf16* hstp_t = hstp + (((t + 1) & 1) << 15);
            asm volatile("global_store_short %0, %1, off sc0 sc1"
                         :: "v"(hstp_t), "v"(hv32) : "memory");
            outp[(size_t)t << 10] = hv;                 // output (fp32, cached)
            asm volatile("s_waitcnt vmcnt(0)" ::: "memory");   // h stores ack'd at coherent point
        }
        __syncthreads();

        // ---- signal arrival: h(t+1) globally visible ----
        if (t + 1 < T_STEPS && tid == 0) {
            unsigned old = __hip_atomic_fetch_add(leaf, 1u, __ATOMIC_RELAXED,
                                                  __HIP_MEMORY_SCOPE_AGENT);
            if ((old & 15u) == 15u)
                __hip_atomic_fetch_add(root, 1u, __ATOMIC_RELAXED,
                                       __HIP_MEMORY_SCOPE_AGENT);   // fire-and-forget
        }
    }
}

extern "C" void kernel_launch(void* const* d_in, const int* in_sizes, int n_in,
                              void* d_out, int out_size, void* d_ws, size_t ws_size,
                              hipStream_t stream) {
    const float* X   = (const float*)d_in[0];
    const float* Wf  = (const float*)d_in[1];
    const float* bWf = (const float*)d_in[2];
    const float* Uf  = (const float*)d_in[3];
    const float* bUf = (const float*)d_in[4];
    const float* Wi  = (const float*)d_in[5];
    const float* bWi = (const float*)d_in[6];
    const float* Ui  = (const float*)d_in[7];
    const float* bUi = (const float*)d_in[8];
    const float* Wo  = (const float*)d_in[9];
    const float* bWo = (const float*)d_in[10];
    const float* Uo  = (const float*)d_in[11];
    const float* bUo = (const float*)d_in[12];
    const float* Wc  = (const float*)d_in[13];
    const float* bWc = (const float*)d_in[14];
    const float* Uc  = (const float*)d_in[15];
    const float* bUc = (const float*)d_in[16];

    char* ws = (char*)d_ws;
    unsigned* cnt = (unsigned*)(ws + WS_CNT);
    bf16* hglob   = (bf16*)(ws + WS_H);
    float* btot   = (float*)(ws + WS_BTOT);
    bf16* Xbf     = (bf16*)(ws + WS_XBF);
    bf16* Bp      = (bf16*)(ws + WS_BPACK);
    float* out    = (float*)d_out;

    hipLaunchKernelGGL(k_init, dim3(16), dim3(256), 0, stream,
                       bWf, bUf, bWi, bUi, bWo, bUo, bWc, bUc, btot, hglob, cnt);
    hipLaunchKernelGGL(k_xpack, dim3(8192), dim3(256), 0, stream, X, Xbf);
    hipLaunchKernelGGL(k_bpack, dim3(3072), dim3(256), 0, stream,
                       Wf, Wi, Wo, Wc, Uf, Ui, Uo, Uc, Bp);
    hipLaunchKernelGGL(k_scan, dim3(NWG), dim3(256), 0, stream,
                       Bp, Xbf, btot, hglob, cnt, out);
}